// Round 7
// baseline (51.317 us; speedup 1.0000x reference)
//
#include <hip/hip_runtime.h>
#include <hip/hip_bf16.h>

#define TOKENS    16384      // B*N = 4*4096
#define DIM       2048
#define NEXP      8
#define NBATCH    4
#define TOK_PER_B 4096
#define ALPHA     0.1f
#define NBLK      512
#define NWAVE     8

// ws layout: per block 16 floats: [0..7] score sums, [8..15] top-k counts.

__device__ __forceinline__ float dot4(float4 a, float4 b) {
    return a.x * b.x + a.y * b.y + a.z * b.z + a.w * b.w;
}

// arg2=2 -> VGPR cap 128 (R5/R6 measured). TPW=4 single pass; chunk loop
// unroll-2 only (R5 lesson: full unroll hoists all x loads -> spill).
__global__ __launch_bounds__(512, 2)
void gate_kernel(const float* __restrict__ x, const float* __restrict__ W,
                 float* __restrict__ out, float* __restrict__ ws)
{
    __shared__ float Wl[NEXP * DIM];          // 64 KiB
    __shared__ float s_part[NWAVE][NEXP];
    __shared__ float s_pcnt[NWAVE][NEXP];

    const int tid = threadIdx.x;

    // Cooperative W load: 4096 float4 across 512 threads -> 8 each.
    {
        const float4* W4   = (const float4*)W;
        float4*       Wl4s = (float4*)Wl;
        #pragma unroll
        for (int i = 0; i < 8; ++i)
            Wl4s[tid + i * 512] = W4[tid + i * 512];
    }
    __syncthreads();

    const int wave = tid >> 6;                     // 0..7
    const int lane = tid & 63;
    const int gw   = blockIdx.x * NWAVE + wave;    // 0..4095
    const int t0   = gw * 4;                       // 4 tokens, same batch
    const bool b0  = lane & 1;
    const bool b1  = lane & 2;
    const bool b2  = lane & 4;
    const bool b4  = lane & 16;
    const bool b5  = lane & 32;
    const int  myexp = lane & 7;
    const int  grp8  = (lane >> 3) * 8;
    // token owned after reduce-scatter: j = 2*bit4 + bit5
    const int  myj   = ((lane >> 4) & 1) * 2 + ((lane >> 5) & 1);

    const float4* Wl4 = (const float4*)Wl;
    const float4* xr  = (const float4*)(x + (size_t)t0 * DIM);

    float acc[4][NEXP];
    #pragma unroll
    for (int j = 0; j < 4; ++j)
        #pragma unroll
        for (int e = 0; e < NEXP; ++e) acc[j][e] = 0.f;

    // 8 dim-chunks of 256 floats; one W LDS read feeds 4 tokens.
    #pragma unroll 2
    for (int i = 0; i < 8; ++i) {
        float4 xc[4];
        #pragma unroll
        for (int j = 0; j < 4; ++j)
            xc[j] = xr[j * (DIM / 4) + i * 64 + lane];   // coalesced 1 KiB/instr
        #pragma unroll
        for (int e = 0; e < NEXP; e += 2) {
            float4 w0 = Wl4[(e    ) * (DIM / 4) + i * 64 + lane];  // conflict-free
            float4 w1 = Wl4[(e + 1) * (DIM / 4) + i * 64 + lane];
            #pragma unroll
            for (int j = 0; j < 4; ++j) {
                acc[j][e]     += dot4(xc[j], w0);
                acc[j][e + 1] += dot4(xc[j], w1);
            }
        }
    }

    // Expert-fold (3 stages) per token + group-pair merge (xor8).
    float r[4];
    #pragma unroll
    for (int j = 0; j < 4; ++j) {
        float m0 = b0 ? acc[j][1] : acc[j][0], s0 = b0 ? acc[j][0] : acc[j][1];
        float m1 = b0 ? acc[j][3] : acc[j][2], s1 = b0 ? acc[j][2] : acc[j][3];
        float m2 = b0 ? acc[j][5] : acc[j][4], s2 = b0 ? acc[j][4] : acc[j][5];
        float m3 = b0 ? acc[j][7] : acc[j][6], s3 = b0 ? acc[j][6] : acc[j][7];
        float k0 = m0 + __shfl_xor(s0, 1, 64);
        float k1 = m1 + __shfl_xor(s1, 1, 64);
        float k2 = m2 + __shfl_xor(s2, 1, 64);
        float k3 = m3 + __shfl_xor(s3, 1, 64);
        float n0 = b1 ? k1 : k0, q0 = b1 ? k0 : k1;
        float n1 = b1 ? k3 : k2, q1 = b1 ? k2 : k3;
        float h0 = n0 + __shfl_xor(q0, 2, 64);
        float h1 = n1 + __shfl_xor(q1, 2, 64);
        float nm = b2 ? h1 : h0, nq = b2 ? h0 : h1;
        float rj = nm + __shfl_xor(nq, 4, 64);
        r[j] = rj + __shfl_xor(rj, 8, 64);     // sum over group-pairs
    }
    // xor16: tokens {0,1} stay in b4=0 lanes, {2,3} go to b4=1 lanes.
    float a_  = b4 ? r[2] : r[0], as_ = b4 ? r[0] : r[2];
    float bb  = b4 ? r[3] : r[1], bs_ = b4 ? r[1] : r[3];
    a_ += __shfl_xor(as_, 16, 64);
    bb += __shfl_xor(bs_, 16, 64);
    // xor32: final split by b5 -> lane holds full logit of (myj, myexp).
    float sel = b5 ? bb : a_, snd = b5 ? a_ : bb;
    float rr  = sel + __shfl_xor(snd, 32, 64);

    // Softmax + top-2 within 8-lane expert group (once for all 4 tokens).
    float m = rr;
    m = fmaxf(m, __shfl_xor(m, 1, 64));
    m = fmaxf(m, __shfl_xor(m, 2, 64));
    m = fmaxf(m, __shfl_xor(m, 4, 64));
    float p = __expf(rr - m);
    float s = p;
    s += __shfl_xor(s, 1, 64);
    s += __shfl_xor(s, 2, 64);
    s += __shfl_xor(s, 4, 64);
    float inv = 1.0f / s;

    unsigned long long bm = __ballot(rr == m);
    int i0 = __ffs((unsigned)((bm >> grp8) & 0xffULL)) - 1;   // jax tie-break
    float rm = (myexp == i0) ? -3.4e38f : rr;
    float mm = rm;
    mm = fmaxf(mm, __shfl_xor(mm, 1, 64));
    mm = fmaxf(mm, __shfl_xor(mm, 2, 64));
    mm = fmaxf(mm, __shfl_xor(mm, 4, 64));
    unsigned long long bm2 = __ballot(rm == mm);
    int i1 = __ffs((unsigned)((bm2 >> grp8) & 0xffULL)) - 1;

    float v0 = inv;                       // exp(m-m)/s
    float v1 = __expf(mm - m) * inv;

    // Aux accumulators: count each (token,expert) once (b3==0 replica only),
    // then fold bits 3,4,5 -> every lane holds per-expert sums over 4 tokens.
    float pacc = (lane & 8) ? 0.f : p * inv;
    float cacc = (lane & 8) ? 0.f : ((myexp == i0 ? 1.f : 0.f) + (myexp == i1 ? 1.f : 0.f));
    pacc += __shfl_xor(pacc, 8, 64);
    pacc += __shfl_xor(pacc, 16, 64);
    pacc += __shfl_xor(pacc, 32, 64);
    cacc += __shfl_xor(cacc, 8, 64);
    cacc += __shfl_xor(cacc, 16, 64);
    cacc += __shfl_xor(cacc, 32, 64);

    if ((lane & 15) == 0) {               // one writer per token quadrant
        const int t = t0 + myj;
        out[(size_t)t * 2 + 0] = v0;
        out[(size_t)t * 2 + 1] = v1;
        out[(size_t)TOKENS * 2 + (size_t)t * 2 + 0] = (float)i0;
        out[(size_t)TOKENS * 2 + (size_t)t * 2 + 1] = (float)i1;
    }

    // Deterministic block reduction: wave partials -> fixed-order sum.
    if (lane < NEXP) {
        s_part[wave][lane] = pacc;
        s_pcnt[wave][lane] = cacc;
    }
    __syncthreads();
    if (tid < NEXP) {
        float sp = 0.f, sc = 0.f;
        #pragma unroll
        for (int w = 0; w < NWAVE; ++w) { sp += s_part[w][tid]; sc += s_pcnt[w][tid]; }
        ws[blockIdx.x * 16 + tid]     = sp;
        ws[blockIdx.x * 16 + 8 + tid] = sc;
    }
}

__global__ void finalize_kernel(const float* __restrict__ ws, float* __restrict__ out)
{
    __shared__ float red[64];
    const int tid = threadIdx.x;
    if (tid < 64) {
        const int b = tid >> 4, c = tid & 15;
        float acc = 0.f;
        #pragma unroll 4
        for (int k = 0; k < 128; ++k)
            acc += ws[(b * 128 + k) * 16 + c];
        red[tid] = acc;
    }
    __syncthreads();
    if (tid == 0) {
        float aux = 0.f;
        for (int b = 0; b < NBATCH; ++b) {
            float a2 = 0.f;
            for (int e = 0; e < NEXP; ++e) {
                float pi = red[b * 16 + e] * (1.f / TOK_PER_B);
                float fi = red[b * 16 + 8 + e] * ((float)NEXP / (2.f * TOK_PER_B));
                a2 += fi * pi;
            }
            aux += a2;
        }
        out[(size_t)TOKENS * 4] = aux * (1.f / NBATCH) * ALPHA;  // out[65536]
    }
}

extern "C" void kernel_launch(void* const* d_in, const int* in_sizes, int n_in,
                              void* d_out, int out_size, void* d_ws, size_t ws_size,
                              hipStream_t stream) {
    const float* x = (const float*)d_in[0];
    const float* W = (const float*)d_in[1];
    float* out = (float*)d_out;
    float* ws  = (float*)d_ws;

    gate_kernel<<<dim3(NBLK), dim3(512), 0, stream>>>(x, W, out, ws);
    finalize_kernel<<<1, 64, 0, stream>>>(ws, out);
}

// Round 8
// 48.942 us; speedup vs baseline: 1.0485x; 1.0485x over previous
//
#include <hip/hip_runtime.h>
#include <hip/hip_bf16.h>

#define TOKENS    16384      // B*N = 4*4096
#define DIM       2048
#define NEXP      8
#define NBATCH    4
#define TOK_PER_B 4096
#define ALPHA     0.1f
#define NBLK      512
#define NWAVE     8

// ws layout: per block 16 floats: [0..7] score sums, [8..15] top-k counts.

__device__ __forceinline__ float dot4(float4 a, float4 b) {
    return a.x * b.x + a.y * b.y + a.z * b.z + a.w * b.w;
}

// arg2=2 -> VGPR cap 128 (R5/R6 measured). Two 2-token passes; chunk loop
// unroll-4 (8 x-loads in flight; full unroll of TPW=4 demanded ~170 regs and
// spilled -- R5). R6 measured: no spill at this structure with unroll-2.
__global__ __launch_bounds__(512, 2)
void gate_kernel(const float* __restrict__ x, const float* __restrict__ W,
                 float* __restrict__ out, float* __restrict__ ws)
{
    __shared__ float Wl[NEXP * DIM];          // 64 KiB
    __shared__ float s_part[NWAVE][NEXP];
    __shared__ float s_pcnt[NWAVE][NEXP];

    const int tid = threadIdx.x;

    // Cooperative W load: 4096 float4 across 512 threads -> 8 each.
    {
        const float4* W4  = (const float4*)W;
        float4*       Wd  = (float4*)Wl;
        #pragma unroll
        for (int i = 0; i < 8; ++i)
            Wd[tid + i * 512] = W4[tid + i * 512];
    }
    __syncthreads();

    const int wave  = tid >> 6;                    // 0..7
    const int lane  = tid & 63;
    const int gw    = blockIdx.x * NWAVE + wave;   // 0..4095
    const int t0    = gw * 4;                      // 4 tokens, same batch
    const bool b0   = lane & 1;
    const bool b1   = lane & 2;
    const bool b2   = lane & 4;
    const int  myexp = lane & 7;
    const int  grp8  = (lane >> 3) * 8;

    float pacc = 0.f, cacc = 0.f;
    const float4* Wl4 = (const float4*)Wl;

    // Two passes of two tokens each: bounds register pressure to the pass.
    #pragma unroll 1
    for (int it = 0; it < 2; ++it) {
        const float4* xr0 = (const float4*)(x + (size_t)(t0 + it * 2) * DIM);
        const float4* xr1 = xr0 + DIM / 4;

        float acc[2][NEXP];
        #pragma unroll
        for (int e = 0; e < NEXP; ++e) { acc[0][e] = 0.f; acc[1][e] = 0.f; }

        // 8 dim-chunks of 256 floats; unroll 4 -> ~8 x-loads in flight.
        #pragma unroll 4
        for (int i = 0; i < 8; ++i) {
            float4 x0 = xr0[i * 64 + lane];        // coalesced 1 KiB/instr
            float4 x1 = xr1[i * 64 + lane];
            #pragma unroll
            for (int e = 0; e < NEXP; e += 2) {
                float4 w0 = Wl4[(e    ) * (DIM / 4) + i * 64 + lane];  // conflict-free
                float4 w1 = Wl4[(e + 1) * (DIM / 4) + i * 64 + lane];
                acc[0][e]     += dot4(x0, w0);
                acc[1][e]     += dot4(x1, w0);
                acc[0][e + 1] += dot4(x0, w1);
                acc[1][e + 1] += dot4(x1, w1);
            }
        }

        // Per-token: reduce-scatter (lane l -> full logit of expert l&7),
        // distributed softmax + top-2 via ballots (verified R3-R7).
        #pragma unroll
        for (int tk = 0; tk < 2; ++tk) {
            float m0 = b0 ? acc[tk][1] : acc[tk][0], s0 = b0 ? acc[tk][0] : acc[tk][1];
            float m1 = b0 ? acc[tk][3] : acc[tk][2], s1 = b0 ? acc[tk][2] : acc[tk][3];
            float m2_ = b0 ? acc[tk][5] : acc[tk][4], s2 = b0 ? acc[tk][4] : acc[tk][5];
            float m3 = b0 ? acc[tk][7] : acc[tk][6], s3 = b0 ? acc[tk][6] : acc[tk][7];
            float k0 = m0 + __shfl_xor(s0, 1, 64);
            float k1 = m1 + __shfl_xor(s1, 1, 64);
            float k2 = m2_ + __shfl_xor(s2, 1, 64);
            float k3 = m3 + __shfl_xor(s3, 1, 64);
            float n0 = b1 ? k1 : k0, q0 = b1 ? k0 : k1;
            float n1 = b1 ? k3 : k2, q1 = b1 ? k2 : k3;
            float h0 = n0 + __shfl_xor(q0, 2, 64);
            float h1 = n1 + __shfl_xor(q1, 2, 64);
            float nm = b2 ? h1 : h0, nq = b2 ? h0 : h1;
            float r  = nm + __shfl_xor(nq, 4, 64);
            r += __shfl_xor(r, 8, 64);
            r += __shfl_xor(r, 16, 64);
            r += __shfl_xor(r, 32, 64);

            float m = r;
            m = fmaxf(m, __shfl_xor(m, 1, 64));
            m = fmaxf(m, __shfl_xor(m, 2, 64));
            m = fmaxf(m, __shfl_xor(m, 4, 64));
            float p = __expf(r - m);
            float s = p;
            s += __shfl_xor(s, 1, 64);
            s += __shfl_xor(s, 2, 64);
            s += __shfl_xor(s, 4, 64);
            float inv = 1.0f / s;

            unsigned long long bm = __ballot(r == m);
            int i0 = __ffs((unsigned)((bm >> grp8) & 0xffULL)) - 1;  // jax tie-break
            float rm = (myexp == i0) ? -3.4e38f : r;
            float mm = rm;
            mm = fmaxf(mm, __shfl_xor(mm, 1, 64));
            mm = fmaxf(mm, __shfl_xor(mm, 2, 64));
            mm = fmaxf(mm, __shfl_xor(mm, 4, 64));
            unsigned long long bm2 = __ballot(rm == mm);
            int i1 = __ffs((unsigned)((bm2 >> grp8) & 0xffULL)) - 1;

            float v0 = inv;
            float v1 = __expf(mm - m) * inv;

            pacc += p * inv;
            cacc += (myexp == i0 ? 1.f : 0.f) + (myexp == i1 ? 1.f : 0.f);

            if (lane == 0) {
                const int t = t0 + it * 2 + tk;
                out[(size_t)t * 2 + 0] = v0;
                out[(size_t)t * 2 + 1] = v1;
                out[(size_t)TOKENS * 2 + (size_t)t * 2 + 0] = (float)i0;
                out[(size_t)TOKENS * 2 + (size_t)t * 2 + 1] = (float)i1;
            }
        }
    }

    // Deterministic block reduction: wave partials -> fixed-order sum.
    if (lane < NEXP) {
        s_part[wave][lane] = pacc;   // lane-groups identical; group 0 used
        s_pcnt[wave][lane] = cacc;
    }
    __syncthreads();
    if (tid < NEXP) {
        float sp = 0.f, sc = 0.f;
        #pragma unroll
        for (int w = 0; w < NWAVE; ++w) { sp += s_part[w][tid]; sc += s_pcnt[w][tid]; }
        ws[blockIdx.x * 16 + tid]     = sp;
        ws[blockIdx.x * 16 + 8 + tid] = sc;
    }
}

// Parallel finalize: 256 threads = 4 slices x 64 cells. Each thread sums 32
// blocks with a FULLY UNROLLED independent-address load chain (32 outstanding
// loads -> ~1-2 memory round trips instead of 32 serial ones).
__global__ void finalize_kernel(const float* __restrict__ ws, float* __restrict__ out)
{
    __shared__ float red[256];
    const int tid  = threadIdx.x;
    const int q    = tid >> 6;          // slice 0..3
    const int cell = tid & 63;          // b*16 + c
    const int b    = cell >> 4;
    const int c    = cell & 15;

    float acc = 0.f;
    #pragma unroll
    for (int k = q; k < 128; k += 4)    // 32 independent loads, fully unrolled
        acc += ws[(size_t)(b * 128 + k) * 16 + c];
    red[tid] = acc;
    __syncthreads();

    if (tid < 64) {
        // fixed order q=0..3 -> deterministic
        float v = red[tid];
        v += red[64 + tid];
        v += red[128 + tid];
        v += red[192 + tid];
        red[tid] = v;
    }
    __syncthreads();

    if (tid == 0) {
        float aux = 0.f;
        for (int bb = 0; bb < NBATCH; ++bb) {
            float a2 = 0.f;
            for (int e = 0; e < NEXP; ++e) {
                float pi = red[bb * 16 + e] * (1.f / TOK_PER_B);
                float fi = red[bb * 16 + 8 + e] * ((float)NEXP / (2.f * TOK_PER_B));
                a2 += fi * pi;
            }
            aux += a2;
        }
        out[(size_t)TOKENS * 4] = aux * (1.f / NBATCH) * ALPHA;  // out[65536]
    }
}

extern "C" void kernel_launch(void* const* d_in, const int* in_sizes, int n_in,
                              void* d_out, int out_size, void* d_ws, size_t ws_size,
                              hipStream_t stream) {
    const float* x = (const float*)d_in[0];
    const float* W = (const float*)d_in[1];
    float* out = (float*)d_out;
    float* ws  = (float*)d_ws;

    gate_kernel<<<dim3(NBLK), dim3(512), 0, stream>>>(x, W, out, ws);
    finalize_kernel<<<1, 256, 0, stream>>>(ws, out);
}